// Round 4
// baseline (1084.830 us; speedup 1.0000x reference)
//
#include <hip/hip_runtime.h>

typedef _Float16 f16;
typedef _Float16 f16x4 __attribute__((ext_vector_type(4)));
typedef _Float16 f16x8 __attribute__((ext_vector_type(8)));
typedef float f32x4 __attribute__((ext_vector_type(4)));

#define S_LEN 2048
#define EMB 1024
#define NH 16
#define HD 64
#define BATCH 2

__device__ __forceinline__ void gload_lds16(const void* g, void* l) {
  __builtin_amdgcn_global_load_lds(
      (const __attribute__((address_space(1))) void*)g,
      (__attribute__((address_space(3))) void*)l, 16, 0, 0);
}

__global__ __launch_bounds__(256) void cast_kernel(const float* __restrict__ in,
                                                   f16* __restrict__ out, int n4) {
  int i = blockIdx.x * 256 + threadIdx.x;
  if (i >= n4) return;
  const float4 v = reinterpret_cast<const float4*>(in)[i];
  f16x4 o;
  o[0] = (f16)v.x; o[1] = (f16)v.y; o[2] = (f16)v.z; o[3] = (f16)v.w;
  reinterpret_cast<f16x4*>(out)[i] = o;
}

// Y = X @ W^T + bias.  X: MxK row-major f16, W: NxK row-major f16.
// MODE 0: write f16 head-split (b,h,s,d) layout.  MODE 1: write fp32 row-major.
template <int MODE>
__global__ __launch_bounds__(256) void gemm_bt(const f16* __restrict__ A,
                                               const f16* __restrict__ Bw,
                                               const float* __restrict__ bias,
                                               void* __restrict__ outp,
                                               int M, int N, int K) {
  __shared__ f16 As[128 * 64];
  __shared__ f16 Bs[64 * 64];
  const int tid = threadIdx.x;
  const int w = tid >> 6, lane = tid & 63;
  const int lg = lane >> 4, l15 = lane & 15;
  const int m0 = blockIdx.y * 128, n0 = blockIdx.x * 64;
  f32x4 acc[2][4] = {};
  for (int k0 = 0; k0 < K; k0 += 64) {
#pragma unroll
    for (int i = 0; i < 4; i++) {  // A tile: 128x64 f16 = 16 chunks of 1KB
      int c = i * 4 + w, o = c * 64 + lane;
      gload_lds16(A + (size_t)(m0 + (o >> 3)) * K + k0 + ((o & 7) << 3), As + c * 512);
    }
#pragma unroll
    for (int i = 0; i < 2; i++) {  // B tile: 64x64 f16 = 8 chunks
      int c = i * 4 + w, o = c * 64 + lane;
      gload_lds16(Bw + (size_t)(n0 + (o >> 3)) * K + k0 + ((o & 7) << 3), Bs + c * 512);
    }
    __syncthreads();
#pragma unroll
    for (int kk = 0; kk < 2; kk++) {
      f16x8 af[2], bf[4];
#pragma unroll
      for (int mi = 0; mi < 2; mi++)
        af[mi] = *(const f16x8*)&As[(w * 32 + mi * 16 + l15) * 64 + kk * 32 + lg * 8];
#pragma unroll
      for (int ni = 0; ni < 4; ni++)
        bf[ni] = *(const f16x8*)&Bs[(ni * 16 + l15) * 64 + kk * 32 + lg * 8];
#pragma unroll
      for (int mi = 0; mi < 2; mi++)
#pragma unroll
        for (int ni = 0; ni < 4; ni++)
          acc[mi][ni] =
              __builtin_amdgcn_mfma_f32_16x16x32_f16(af[mi], bf[ni], acc[mi][ni], 0, 0, 0);
    }
    __syncthreads();
  }
#pragma unroll
  for (int mi = 0; mi < 2; mi++)
#pragma unroll
    for (int ni = 0; ni < 4; ni++) {
      const int gn = n0 + ni * 16 + l15;
      const float bv = bias[gn];
#pragma unroll
      for (int r = 0; r < 4; r++) {
        const int gm = m0 + w * 32 + mi * 16 + lg * 4 + r;
        const float v = acc[mi][ni][r] + bv;
        if (MODE == 1) {
          ((float*)outp)[(size_t)gm * N + gn] = v;
        } else {
          const int b = gm >> 11, s = gm & 2047;
          const int h = gn >> 6, d = gn & 63;
          ((f16*)outp)[(((size_t)(b * NH + h)) * S_LEN + s) * HD + d] = (f16)v;
        }
      }
    }
}

// One block = 64 q-rows of one (b,h).  4 waves x 16 rows.
// Phase 1: running (m,l) via online softmax, K read direct from global (L2).
// Phase 2: recompute scores, write normalized attn fp32, PV via LDS P/V^T.
__global__ __launch_bounds__(256) void attn_kernel(const f16* __restrict__ Qp,
                                                   const f16* __restrict__ Kp,
                                                   const f16* __restrict__ Vp,
                                                   float* __restrict__ attn_out,
                                                   f16* __restrict__ ctx_out) {
  __shared__ f16 Vt[64 * 136];      // V^T tile [d][key], stride 136 (16B-aligned)
  __shared__ f16 Ps[4][16 * 136];   // per-wave P tile [qrow][key]
  const int tid = threadIdx.x;
  const int w = tid >> 6, lane = tid & 63;
  const int lg = lane >> 4, l15 = lane & 15;
  const int bh = blockIdx.y;
  const int b = bh >> 4, h = bh & 15;
  const int q0 = blockIdx.x * 64;
  const f16* Qbh = Qp + (size_t)bh * S_LEN * HD;
  const f16* Kbh = Kp + (size_t)bh * S_LEN * HD;
  const f16* Vbh = Vp + (size_t)bh * S_LEN * HD;
  const int qrow_base = q0 + w * 16;

  f16x8 qf[2];
#pragma unroll
  for (int kk = 0; kk < 2; kk++)
    qf[kk] = *(const f16x8*)&Qbh[(size_t)(qrow_base + l15) * HD + kk * 32 + lg * 8];

  float m[4], l[4];
#pragma unroll
  for (int r = 0; r < 4; r++) { m[r] = -1e30f; l[r] = 0.f; }

  // ---------- phase 1: softmax stats (barrier-free) ----------
  for (int kt = 0; kt < S_LEN; kt += 128) {
    f32x4 sf[8] = {};
#pragma unroll
    for (int kk = 0; kk < 2; kk++)
#pragma unroll
      for (int nf = 0; nf < 8; nf++) {
        f16x8 kf = *(const f16x8*)&Kbh[(size_t)(kt + nf * 16 + l15) * HD + kk * 32 + lg * 8];
        sf[nf] = __builtin_amdgcn_mfma_f32_16x16x32_f16(qf[kk], kf, sf[nf], 0, 0, 0);
      }
#pragma unroll
    for (int r = 0; r < 4; r++) {
      float pm = sf[0][r];
#pragma unroll
      for (int nf = 1; nf < 8; nf++) pm = fmaxf(pm, sf[nf][r]);
      pm *= 0.125f;
#pragma unroll
      for (int ofs = 1; ofs < 16; ofs <<= 1) pm = fmaxf(pm, __shfl_xor(pm, ofs));
      const float mn = fmaxf(m[r], pm);
      float ps = 0.f;
#pragma unroll
      for (int nf = 0; nf < 8; nf++) ps += __expf(sf[nf][r] * 0.125f - mn);
#pragma unroll
      for (int ofs = 1; ofs < 16; ofs <<= 1) ps += __shfl_xor(ps, ofs);
      l[r] = l[r] * __expf(m[r] - mn) + ps;
      m[r] = mn;
    }
  }
  float invl[4];
#pragma unroll
  for (int r = 0; r < 4; r++) invl[r] = 1.0f / l[r];

  // ---------- phase 2: attn write + PV ----------
  f32x4 cacc[4] = {};
  for (int kt = 0; kt < S_LEN; kt += 128) {
    // stage V transposed: [key][d] global -> [d][key] LDS
#pragma unroll
    for (int i = 0; i < 4; i++) {
      int ch = i * 256 + tid;            // 0..1023 chunks of 8 f16
      int ky = ch >> 3, d0 = (ch & 7) << 3;
      f16x8 v = *(const f16x8*)&Vbh[(size_t)(kt + ky) * HD + d0];
#pragma unroll
      for (int j = 0; j < 8; j++) Vt[(d0 + j) * 136 + ky] = v[j];
    }
    __syncthreads();

    f32x4 sf[8] = {};
#pragma unroll
    for (int kk = 0; kk < 2; kk++)
#pragma unroll
      for (int nf = 0; nf < 8; nf++) {
        f16x8 kf = *(const f16x8*)&Kbh[(size_t)(kt + nf * 16 + l15) * HD + kk * 32 + lg * 8];
        sf[nf] = __builtin_amdgcn_mfma_f32_16x16x32_f16(qf[kk], kf, sf[nf], 0, 0, 0);
      }
#pragma unroll
    for (int nf = 0; nf < 8; nf++)
#pragma unroll
      for (int r = 0; r < 4; r++) {
        const float p = __expf(sf[nf][r] * 0.125f - m[r]) * invl[r];
        const int qrow = qrow_base + lg * 4 + r;
        attn_out[((size_t)bh * S_LEN + qrow) * S_LEN + kt + nf * 16 + l15] = p;
        Ps[w][(lg * 4 + r) * 136 + nf * 16 + l15] = (f16)p;
      }
    // PV: ctx(16x64) += P(16x128) @ V(128x64)
#pragma unroll
    for (int kk2 = 0; kk2 < 4; kk2++) {
      f16x8 pf = *(const f16x8*)&Ps[w][l15 * 136 + kk2 * 32 + lg * 8];
#pragma unroll
      for (int nf2 = 0; nf2 < 4; nf2++) {
        f16x8 vf = *(const f16x8*)&Vt[(nf2 * 16 + l15) * 136 + kk2 * 32 + lg * 8];
        cacc[nf2] = __builtin_amdgcn_mfma_f32_16x16x32_f16(pf, vf, cacc[nf2], 0, 0, 0);
      }
    }
    __syncthreads();
  }
#pragma unroll
  for (int nf2 = 0; nf2 < 4; nf2++)
#pragma unroll
    for (int r = 0; r < 4; r++) {
      const int qrow = qrow_base + lg * 4 + r;
      const int gr = b * S_LEN + qrow;
      const int gc = h * HD + nf2 * 16 + l15;
      ctx_out[(size_t)gr * EMB + gc] = (f16)cacc[nf2][r];
    }
}

extern "C" void kernel_launch(void* const* d_in, const int* in_sizes, int n_in,
                              void* d_out, int out_size, void* d_ws, size_t ws_size,
                              hipStream_t stream) {
  const float* query = (const float*)d_in[0];
  const float* key_i = (const float*)d_in[1];
  const float* value = (const float*)d_in[2];
  const float* Wq = (const float*)d_in[3];
  const float* bq = (const float*)d_in[4];
  const float* Wk = (const float*)d_in[5];
  const float* bk = (const float*)d_in[6];
  const float* Wv = (const float*)d_in[7];
  const float* bv = (const float*)d_in[8];
  const float* Wo = (const float*)d_in[9];
  const float* bo = (const float*)d_in[10];

  float* out = (float*)d_out;
  float* attn = out + (size_t)BATCH * S_LEN * EMB;

  f16* ws = (f16*)d_ws;
  const size_t NTOK = (size_t)BATCH * S_LEN;  // 4096
  f16* Qh = ws;
  f16* Kh = Qh + NTOK * EMB;
  f16* Vh = Kh + NTOK * EMB;
  f16* Wqh = Vh + NTOK * EMB;
  f16* Wkh = Wqh + (size_t)EMB * EMB;
  f16* Wvh = Wkh + (size_t)EMB * EMB;
  f16* Woh = Wvh + (size_t)EMB * EMB;
  f16* Qp = Woh + (size_t)EMB * EMB;
  f16* Kp = Qp + NTOK * EMB;
  f16* Vp = Kp + NTOK * EMB;
  f16* ctx = Vp + NTOK * EMB;   // total 32M f16 = 64 MB

  const int n4_x = (int)(NTOK * EMB / 4);         // 1048576
  const int n4_w = (int)((size_t)EMB * EMB / 4);  // 262144
  cast_kernel<<<n4_x / 256, 256, 0, stream>>>(query, Qh, n4_x);
  cast_kernel<<<n4_x / 256, 256, 0, stream>>>(key_i, Kh, n4_x);
  cast_kernel<<<n4_x / 256, 256, 0, stream>>>(value, Vh, n4_x);
  cast_kernel<<<n4_w / 256, 256, 0, stream>>>(Wq, Wqh, n4_w);
  cast_kernel<<<n4_w / 256, 256, 0, stream>>>(Wk, Wkh, n4_w);
  cast_kernel<<<n4_w / 256, 256, 0, stream>>>(Wv, Wvh, n4_w);
  cast_kernel<<<n4_w / 256, 256, 0, stream>>>(Wo, Woh, n4_w);

  dim3 ggrid(EMB / 64, (unsigned)(NTOK / 128));  // (16, 32)
  gemm_bt<0><<<ggrid, 256, 0, stream>>>(Qh, Wqh, bq, Qp, (int)NTOK, EMB, EMB);
  gemm_bt<0><<<ggrid, 256, 0, stream>>>(Kh, Wkh, bk, Kp, (int)NTOK, EMB, EMB);
  gemm_bt<0><<<ggrid, 256, 0, stream>>>(Vh, Wvh, bv, Vp, (int)NTOK, EMB, EMB);

  attn_kernel<<<dim3(S_LEN / 64, BATCH * NH), 256, 0, stream>>>(Qp, Kp, Vp, attn, ctx);

  gemm_bt<1><<<ggrid, 256, 0, stream>>>(ctx, Woh, bo, out, (int)NTOK, EMB, EMB);
}

// Round 9
// 970.121 us; speedup vs baseline: 1.1182x; 1.1182x over previous
//
#include <hip/hip_runtime.h>

typedef _Float16 f16;
typedef _Float16 f16x4 __attribute__((ext_vector_type(4)));
typedef _Float16 f16x8 __attribute__((ext_vector_type(8)));
typedef float f32x4 __attribute__((ext_vector_type(4)));

#define S_LEN 2048
#define EMB 1024
#define NH 16
#define HD 64
#define BATCH 2

__device__ __forceinline__ void gload_lds16(const void* g, void* l) {
  __builtin_amdgcn_global_load_lds(
      (const __attribute__((address_space(1))) void*)g,
      (__attribute__((address_space(3))) void*)l, 16, 0, 0);
}

__global__ __launch_bounds__(256) void cast_kernel(const float* __restrict__ in,
                                                   f16* __restrict__ out, int n4) {
  int i = blockIdx.x * 256 + threadIdx.x;
  if (i >= n4) return;
  const float4 v = reinterpret_cast<const float4*>(in)[i];
  f16x4 o;
  o[0] = (f16)v.x; o[1] = (f16)v.y; o[2] = (f16)v.z; o[3] = (f16)v.w;
  reinterpret_cast<f16x4*>(out)[i] = o;
}

// Y = X @ W^T + bias.  X: MxK row-major f16, W: NxK row-major f16.
// MODE 0: write f16 head-split (b,h,s,d).  MODE 1: fp32 row-major.
// MODE 2: write f16 transposed head-split (b,h,d,s)  [for V].
template <int MODE>
__global__ __launch_bounds__(256) void gemm_bt(const f16* __restrict__ A,
                                               const f16* __restrict__ Bw,
                                               const float* __restrict__ bias,
                                               void* __restrict__ outp,
                                               int M, int N, int K) {
  __shared__ f16 As[128 * 64];
  __shared__ f16 Bs[64 * 64];
  const int tid = threadIdx.x;
  const int w = tid >> 6, lane = tid & 63;
  const int lg = lane >> 4, l15 = lane & 15;
  const int m0 = blockIdx.y * 128, n0 = blockIdx.x * 64;
  f32x4 acc[2][4] = {};
  for (int k0 = 0; k0 < K; k0 += 64) {
#pragma unroll
    for (int i = 0; i < 4; i++) {  // A tile: 128x64 f16 = 16 chunks of 1KB
      int c = i * 4 + w, o = c * 64 + lane;
      gload_lds16(A + (size_t)(m0 + (o >> 3)) * K + k0 + ((o & 7) << 3), As + c * 512);
    }
#pragma unroll
    for (int i = 0; i < 2; i++) {  // B tile: 64x64 f16 = 8 chunks
      int c = i * 4 + w, o = c * 64 + lane;
      gload_lds16(Bw + (size_t)(n0 + (o >> 3)) * K + k0 + ((o & 7) << 3), Bs + c * 512);
    }
    __syncthreads();
#pragma unroll
    for (int kk = 0; kk < 2; kk++) {
      f16x8 af[2], bf[4];
#pragma unroll
      for (int mi = 0; mi < 2; mi++)
        af[mi] = *(const f16x8*)&As[(w * 32 + mi * 16 + l15) * 64 + kk * 32 + lg * 8];
#pragma unroll
      for (int ni = 0; ni < 4; ni++)
        bf[ni] = *(const f16x8*)&Bs[(ni * 16 + l15) * 64 + kk * 32 + lg * 8];
#pragma unroll
      for (int mi = 0; mi < 2; mi++)
#pragma unroll
        for (int ni = 0; ni < 4; ni++)
          acc[mi][ni] =
              __builtin_amdgcn_mfma_f32_16x16x32_f16(af[mi], bf[ni], acc[mi][ni], 0, 0, 0);
    }
    __syncthreads();
  }
#pragma unroll
  for (int mi = 0; mi < 2; mi++)
#pragma unroll
    for (int ni = 0; ni < 4; ni++) {
      const int gn = n0 + ni * 16 + l15;
      const float bv = bias[gn];
#pragma unroll
      for (int r = 0; r < 4; r++) {
        const int gm = m0 + w * 32 + mi * 16 + lg * 4 + r;
        const float v = acc[mi][ni][r] + bv;
        if (MODE == 1) {
          ((float*)outp)[(size_t)gm * N + gn] = v;
        } else {
          const int b = gm >> 11, s = gm & 2047;
          const int h = gn >> 6, d = gn & 63;
          if (MODE == 0)
            ((f16*)outp)[(((size_t)(b * NH + h)) * S_LEN + s) * HD + d] = (f16)v;
          else  // MODE 2: (b,h,d,s)
            ((f16*)outp)[(((size_t)(b * NH + h)) * HD + d) * S_LEN + s] = (f16)v;
        }
      }
    }
}

// One block = 64 q-rows of one (b,h).  4 waves x 16 rows.
// Phase 1: running (m,l) online-softmax in exp2 domain; K direct from global/L2.
// Phase 2: recompute scores, write normalized attn fp32, PV with:
//   - V tile reg-staged from VtG (b,h,d,s) then XOR-swizzled ds_write_b128 (T2/T14)
//   - raw s_barrier + lgkm-only fences (no vmcnt drain: stores/loads fly across)
__global__ __launch_bounds__(256) void attn_kernel(const f16* __restrict__ Qp,
                                                   const f16* __restrict__ Kp,
                                                   const f16* __restrict__ VtG,
                                                   float* __restrict__ attn_out,
                                                   f16* __restrict__ ctx_out) {
  __shared__ f16 Vt[64 * 128];     // swizzled: row d, 16B-block b at byte r*256+((b^(r&7))<<4)
  __shared__ f16 Ps[4][16 * 136];  // per-wave P tile [qrow][key]
  const int tid = threadIdx.x;
  const int w = tid >> 6, lane = tid & 63;
  const int lg = lane >> 4, l15 = lane & 15;
  const int bh = blockIdx.y;
  const int b = bh >> 4, h = bh & 15;
  const int q0 = blockIdx.x * 64;
  const f16* Qbh = Qp + (size_t)bh * S_LEN * HD;
  const f16* Kbh = Kp + (size_t)bh * S_LEN * HD;
  const f16* Vtbh = VtG + (size_t)bh * HD * S_LEN;
  const int qrow_base = q0 + w * 16;

  f16x8 qf[2];
  const f16 qsc = (f16)0.18033688f;  // 0.125 * log2(e): scores in exp2 domain
#pragma unroll
  for (int kk = 0; kk < 2; kk++) {
    qf[kk] = *(const f16x8*)&Qbh[(size_t)(qrow_base + l15) * HD + kk * 32 + lg * 8];
#pragma unroll
    for (int j = 0; j < 8; j++) qf[kk][j] *= qsc;
  }

  float m2[4], l[4];
#pragma unroll
  for (int r = 0; r < 4; r++) { m2[r] = -1e30f; l[r] = 0.f; }

  // ---------- phase 1: softmax stats (no barriers, no LDS) ----------
  for (int kt = 0; kt < S_LEN; kt += 128) {
    f32x4 sf[8] = {};
#pragma unroll
    for (int kk = 0; kk < 2; kk++)
#pragma unroll
      for (int nf = 0; nf < 8; nf++) {
        f16x8 kf = *(const f16x8*)&Kbh[(size_t)(kt + nf * 16 + l15) * HD + kk * 32 + lg * 8];
        sf[nf] = __builtin_amdgcn_mfma_f32_16x16x32_f16(qf[kk], kf, sf[nf], 0, 0, 0);
      }
#pragma unroll
    for (int r = 0; r < 4; r++) {
      float pm = sf[0][r];
#pragma unroll
      for (int nf = 1; nf < 8; nf++) pm = fmaxf(pm, sf[nf][r]);
#pragma unroll
      for (int ofs = 1; ofs < 16; ofs <<= 1) pm = fmaxf(pm, __shfl_xor(pm, ofs));
      const float mn = fmaxf(m2[r], pm);
      float ps = 0.f;
#pragma unroll
      for (int nf = 0; nf < 8; nf++) ps += exp2f(sf[nf][r] - mn);
#pragma unroll
      for (int ofs = 1; ofs < 16; ofs <<= 1) ps += __shfl_xor(ps, ofs);
      l[r] = l[r] * exp2f(m2[r] - mn) + ps;
      m2[r] = mn;
    }
  }
#pragma unroll
  for (int r = 0; r < 4; r++) m2[r] += log2f(l[r]);  // fold 1/l into exponent

#define STAGE_LOAD(KT)                                                      \
  {                                                                         \
    _Pragma("unroll") for (int c = 0; c < 4; c++) {                         \
      const int idx = c * 256 + tid;                                        \
      const int rr = idx >> 4, bb = idx & 15;                               \
      vreg[c] = *(const f16x8*)&Vtbh[(size_t)rr * S_LEN + (KT) + bb * 8];   \
    }                                                                       \
  }
#define STAGE_WRITE()                                                       \
  {                                                                         \
    _Pragma("unroll") for (int c = 0; c < 4; c++) {                         \
      const int idx = c * 256 + tid;                                        \
      const int rr = idx >> 4, bb = idx & 15;                               \
      *(f16x8*)((char*)Vt + rr * 256 + ((bb ^ (rr & 7)) << 4)) = vreg[c];   \
    }                                                                       \
  }

  // ---------- phase 2: attn write + PV ----------
  f32x4 cacc[4] = {};
  f16x8 vreg[4];
  STAGE_LOAD(0);
  STAGE_WRITE();
  asm volatile("s_waitcnt lgkmcnt(0)\n\ts_barrier" ::: "memory");  // Vt tile 0 ready

  for (int t = 0; t < 16; t++) {
    const int kt = t * 128;
    STAGE_LOAD(((t + 1) & 15) * 128);  // issue next tile's loads early (T14)

    f32x4 sf[8] = {};
#pragma unroll
    for (int kk = 0; kk < 2; kk++)
#pragma unroll
      for (int nf = 0; nf < 8; nf++) {
        f16x8 kf = *(const f16x8*)&Kbh[(size_t)(kt + nf * 16 + l15) * HD + kk * 32 + lg * 8];
        sf[nf] = __builtin_amdgcn_mfma_f32_16x16x32_f16(qf[kk], kf, sf[nf], 0, 0, 0);
      }
#pragma unroll
    for (int nf = 0; nf < 8; nf++)
#pragma unroll
      for (int r = 0; r < 4; r++) {
        const float p = exp2f(sf[nf][r] - m2[r]);
        const int qrow = qrow_base + lg * 4 + r;
        attn_out[((size_t)bh * S_LEN + qrow) * S_LEN + kt + nf * 16 + l15] = p;
        Ps[w][(lg * 4 + r) * 136 + nf * 16 + l15] = (f16)p;
      }
    // PV: ctx(16x64) += P(16x128) @ V(128x64); Vt read swizzle matches write swizzle
#pragma unroll
    for (int kk2 = 0; kk2 < 4; kk2++) {
      f16x8 pf = *(const f16x8*)&Ps[w][l15 * 136 + kk2 * 32 + lg * 8];
#pragma unroll
      for (int nf2 = 0; nf2 < 4; nf2++) {
        const int rr = nf2 * 16 + l15, bb = kk2 * 4 + lg;
        f16x8 vf = *(const f16x8*)((const char*)Vt + rr * 256 + ((bb ^ (rr & 7)) << 4));
        cacc[nf2] = __builtin_amdgcn_mfma_f32_16x16x32_f16(pf, vf, cacc[nf2], 0, 0, 0);
      }
    }
    asm volatile("s_barrier" ::: "memory");  // all waves done reading Vt (reads consumed)
    STAGE_WRITE();
    asm volatile("s_waitcnt lgkmcnt(0)\n\ts_barrier" ::: "memory");  // next tile visible
  }
#pragma unroll
  for (int nf2 = 0; nf2 < 4; nf2++)
#pragma unroll
    for (int r = 0; r < 4; r++) {
      const int qrow = qrow_base + lg * 4 + r;
      const int gr = b * S_LEN + qrow;
      const int gc = h * HD + nf2 * 16 + l15;
      ctx_out[(size_t)gr * EMB + gc] = (f16)cacc[nf2][r];
    }
#undef STAGE_LOAD
#undef STAGE_WRITE
}

extern "C" void kernel_launch(void* const* d_in, const int* in_sizes, int n_in,
                              void* d_out, int out_size, void* d_ws, size_t ws_size,
                              hipStream_t stream) {
  const float* query = (const float*)d_in[0];
  const float* key_i = (const float*)d_in[1];
  const float* value = (const float*)d_in[2];
  const float* Wq = (const float*)d_in[3];
  const float* bq = (const float*)d_in[4];
  const float* Wk = (const float*)d_in[5];
  const float* bk = (const float*)d_in[6];
  const float* Wv = (const float*)d_in[7];
  const float* bv = (const float*)d_in[8];
  const float* Wo = (const float*)d_in[9];
  const float* bo = (const float*)d_in[10];

  float* out = (float*)d_out;
  float* attn = out + (size_t)BATCH * S_LEN * EMB;

  f16* ws = (f16*)d_ws;
  const size_t NTOK = (size_t)BATCH * S_LEN;  // 4096
  f16* Qh = ws;
  f16* Kh = Qh + NTOK * EMB;
  f16* Vh = Kh + NTOK * EMB;
  f16* Wqh = Vh + NTOK * EMB;
  f16* Wkh = Wqh + (size_t)EMB * EMB;
  f16* Wvh = Wkh + (size_t)EMB * EMB;
  f16* Woh = Wvh + (size_t)EMB * EMB;
  f16* Qp = Woh + (size_t)EMB * EMB;
  f16* Kp = Qp + NTOK * EMB;
  f16* VtG = Kp + NTOK * EMB;   // V projection, stored (b,h,d,s)
  f16* ctx = VtG + NTOK * EMB;  // total 32M f16 = 64 MB

  const int n4_x = (int)(NTOK * EMB / 4);         // 1048576
  const int n4_w = (int)((size_t)EMB * EMB / 4);  // 262144
  cast_kernel<<<n4_x / 256, 256, 0, stream>>>(query, Qh, n4_x);
  cast_kernel<<<n4_x / 256, 256, 0, stream>>>(key_i, Kh, n4_x);
  cast_kernel<<<n4_x / 256, 256, 0, stream>>>(value, Vh, n4_x);
  cast_kernel<<<n4_w / 256, 256, 0, stream>>>(Wq, Wqh, n4_w);
  cast_kernel<<<n4_w / 256, 256, 0, stream>>>(Wk, Wkh, n4_w);
  cast_kernel<<<n4_w / 256, 256, 0, stream>>>(Wv, Wvh, n4_w);
  cast_kernel<<<n4_w / 256, 256, 0, stream>>>(Wo, Woh, n4_w);

  dim3 ggrid(EMB / 64, (unsigned)(NTOK / 128));  // (16, 32)
  gemm_bt<0><<<ggrid, 256, 0, stream>>>(Qh, Wqh, bq, Qp, (int)NTOK, EMB, EMB);
  gemm_bt<0><<<ggrid, 256, 0, stream>>>(Kh, Wkh, bk, Kp, (int)NTOK, EMB, EMB);
  gemm_bt<2><<<ggrid, 256, 0, stream>>>(Vh, Wvh, bv, VtG, (int)NTOK, EMB, EMB);

  attn_kernel<<<dim3(S_LEN / 64, BATCH * NH), 256, 0, stream>>>(Qp, Kp, VtG, attn, ctx);

  gemm_bt<1><<<ggrid, 256, 0, stream>>>(ctx, Woh, bo, out, (int)NTOK, EMB, EMB);
}